// Round 1
// baseline (172.261 us; speedup 1.0000x reference)
//
#include <hip/hip_runtime.h>

// Depthwise causal conv1d, k=3.
// x: (8, 768, 4096) fp32, weight: (768, 1, 3) fp32, y: (8, 768, 4096) fp32.
// y[n,c,t] = w[c,0]*x[t-2] + w[c,1]*x[t-1] + w[c,2]*x[t], zeros left of t=0.
//
// Memory-bound: ~201 MB total traffic -> floor ~32 us at 6.3 TB/s.
// One thread per float4 of output: 16B vector load + 2 scalar history loads
// (L1 hits, they alias the neighboring float4) + 16B vector store.

#define CONV_L    4096
#define CONV_L4   1024   // CONV_L / 4
#define CONV_C    768

__global__ __launch_bounds__(256) void dwconv1d_k3_kernel(
    const float* __restrict__ x,
    const float* __restrict__ w,
    float* __restrict__ y,
    int total4)
{
    int idx = blockIdx.x * blockDim.x + threadIdx.x;
    if (idx >= total4) return;

    int row = idx >> 10;          // idx / CONV_L4
    int p4  = idx & (CONV_L4 - 1);
    int c   = row - (row / CONV_C) * CONV_C;   // row % 768 (magic-mul)

    const float w0 = w[c * 3 + 0];
    const float w1 = w[c * 3 + 1];
    const float w2 = w[c * 3 + 2];

    const float* xrow = x + (size_t)row * CONV_L;
    float4 cur = ((const float4*)xrow)[p4];

    float xm1 = 0.0f, xm2 = 0.0f;
    if (p4 != 0) {
        const float* xs = xrow + (p4 << 2);
        xm1 = xs[-1];
        xm2 = xs[-2];
    }

    float4 out;
    out.x = w0 * xm2   + w1 * xm1   + w2 * cur.x;
    out.y = w0 * xm1   + w1 * cur.x + w2 * cur.y;
    out.z = w0 * cur.x + w1 * cur.y + w2 * cur.z;
    out.w = w0 * cur.y + w1 * cur.z + w2 * cur.w;

    ((float4*)(y + (size_t)row * CONV_L))[p4] = out;
}

extern "C" void kernel_launch(void* const* d_in, const int* in_sizes, int n_in,
                              void* d_out, int out_size, void* d_ws, size_t ws_size,
                              hipStream_t stream)
{
    const float* x = (const float*)d_in[0];
    const float* w = (const float*)d_in[1];
    float* y = (float*)d_out;

    const int total4 = out_size / 4;              // 8*768*4096/4 = 6,291,456
    const int block = 256;
    const int grid = (total4 + block - 1) / block; // 24576 blocks

    dwconv1d_k3_kernel<<<grid, block, 0, stream>>>(x, w, y, total4);
}

// Round 2
// 172.052 us; speedup vs baseline: 1.0012x; 1.0012x over previous
//
#include <hip/hip_runtime.h>

// Depthwise causal conv1d, k=3.
// x: (8, 768, 4096) fp32, weight: (768, 1, 3) fp32, y: (8, 768, 4096) fp32.
// y[n,c,t] = w[c,0]*x[t-2] + w[c,1]*x[t-1] + w[c,2]*x[t], zeros left of t=0.
//
// Memory-bound: ~201 MB total traffic -> floor ~30 us at measured 6.8 TB/s.
// One thread per float4. History (x[t-1], x[t-2]) comes from the previous
// lane via __shfl_up; only lane 0 of each wave touches global for history.
// row (hence channel c) is block-uniform -> weight loads compile to s_load.

#define CONV_L 4096
#define CONV_C 768

typedef float vfloat4 __attribute__((ext_vector_type(4)));

__global__ __launch_bounds__(256) void dwconv1d_k3_kernel(
    const float* __restrict__ x,
    const float* __restrict__ w,
    float* __restrict__ y)
{
    // 4 blocks of 256 threads per row (1024 float4 per row).
    const int row = blockIdx.x >> 2;                      // block-uniform
    const int p4  = ((blockIdx.x & 3) << 8) + threadIdx.x;
    const int c   = row % CONV_C;                         // uniform -> scalar

    const float w0 = w[c * 3 + 0];
    const float w1 = w[c * 3 + 1];
    const float w2 = w[c * 3 + 2];

    const float* xrow = x + (size_t)row * CONV_L;
    const float4 cur = ((const float4*)xrow)[p4];

    // History from previous lane (its cur.w = x[t-1], cur.z = x[t-2]).
    float xm1 = __shfl_up(cur.w, 1);
    float xm2 = __shfl_up(cur.z, 1);
    if ((threadIdx.x & 63) == 0) {
        if (p4 == 0) {
            xm1 = 0.0f; xm2 = 0.0f;                       // causal left edge
        } else {
            const float* xs = xrow + (p4 << 2);
            xm1 = xs[-1]; xm2 = xs[-2];
        }
    }

    vfloat4 out;
    out.x = w0 * xm2   + w1 * xm1   + w2 * cur.x;
    out.y = w0 * xm1   + w1 * cur.x + w2 * cur.y;
    out.z = w0 * cur.x + w1 * cur.y + w2 * cur.z;
    out.w = w0 * cur.y + w1 * cur.z + w2 * cur.w;

    __builtin_nontemporal_store(out,
        (vfloat4*)(y + (size_t)row * CONV_L + ((size_t)p4 << 2)));
}

extern "C" void kernel_launch(void* const* d_in, const int* in_sizes, int n_in,
                              void* d_out, int out_size, void* d_ws, size_t ws_size,
                              hipStream_t stream)
{
    const float* x = (const float*)d_in[0];
    const float* w = (const float*)d_in[1];
    float* y = (float*)d_out;

    const int rows = out_size / CONV_L;   // 8*768 = 6144
    const int grid = rows * 4;            // 4 blocks per row, 256 thr each
    dwconv1d_k3_kernel<<<grid, 256, 0, stream>>>(x, w, y);
}